// Round 1
// baseline (7287.094 us; speedup 1.0000x reference)
//
#include <hip/hip_runtime.h>
#include <stdint.h>

// Problem dims
#define S_LEN 256
#define BATCH 512
#define HID   256
#define CH    64            // timestep chunk for gi precompute
#define NCH   (S_LEN/CH)

// ---------------- workspace layout (floats) ----------------
#define OFF_GI    0ull
#define N_GI      ((size_t)CH*BATCH*768)        // 25,165,824
#define OFF_H     (OFF_GI + N_GI)
#define N_H       ((size_t)2*BATCH*HID)         // double-buffered hidden
#define OFF_PROBS (OFF_H + N_H)
#define N_PROBS   ((size_t)S_LEN*BATCH*6)
#define OFF_PUSH  (OFF_PROBS + N_PROBS)
#define N_PUSH    ((size_t)S_LEN*BATCH*128)
#define OFF_ARAW  (OFF_PUSH + N_PUSH)
#define N_ARAW    ((size_t)S_LEN*BATCH)
#define OFF_FLAGS (OFF_ARAW + N_ARAW)
#define N_FLAGS   256ull
#define WS_FLOATS (OFF_FLAGS + N_FLAGS)

// =====================================================================
// Generic 128x128x256 fp32 GEMM, A is [M,256] (maybe gathered/shifted),
// W is [N][256] row-major (we compute A @ W^T).
// MODE 0: A = masked embedding gather (gi precompute), out = A@W^T + bias
// MODE 1: A = outputs shifted by one timestep, out = tanh(A@W^T + bias)
// MODE 2: A = outputs, epilogue: araw[m] += sum_n tanh(C+ba1[n])*Wa2[n]
// =====================================================================
template<int MODE>
__global__ __launch_bounds__(256)
void k_gemm(const float* __restrict__ Asrc,
            const int*   __restrict__ tok,
            const float* __restrict__ emb,
            const float* __restrict__ W,
            const float* __restrict__ bias,
            const float* __restrict__ Wa2,
            float* __restrict__ out)
{
  const int tid   = threadIdx.x;
  const int mbase = blockIdx.x * 128;
  const int nbase = blockIdx.y * 128;
  __shared__ float As[16][132];
  __shared__ float Bs[16][132];
  const int tm = tid & 15, tn = tid >> 4;

  float acc[8][8];
  #pragma unroll
  for (int i = 0; i < 8; i++)
    #pragma unroll
    for (int j = 0; j < 8; j++) acc[i][j] = 0.f;

  const int a_m = tid & 127, a_k0 = (tid >> 7) << 3;   // 2 threads per row, 8 k each
  const int b_n = tid & 127, b_k0 = a_k0;

  const float* arow;
  if (MODE == 0) {
    int t = tok[mbase + a_m];
    arow = (t == 0) ? nullptr : (emb + (size_t)t * HID);        // PAD mask
  } else if (MODE == 1) {
    int m = mbase + a_m;
    arow = (m < BATCH) ? nullptr : (Asrc + (size_t)(m - BATCH) * HID); // h_{t-1}; t=0 -> 0
  } else {
    arow = Asrc + (size_t)(mbase + a_m) * HID;
  }
  const float* brow = W + (size_t)(nbase + b_n) * HID;

  for (int kc = 0; kc < 256; kc += 16) {
    float av8[8], bv8[8];
    if (arow) {
      const float4 x0 = *(const float4*)(arow + kc + a_k0);
      const float4 x1 = *(const float4*)(arow + kc + a_k0 + 4);
      av8[0]=x0.x; av8[1]=x0.y; av8[2]=x0.z; av8[3]=x0.w;
      av8[4]=x1.x; av8[5]=x1.y; av8[6]=x1.z; av8[7]=x1.w;
    } else {
      #pragma unroll
      for (int i = 0; i < 8; i++) av8[i] = 0.f;
    }
    {
      const float4 y0 = *(const float4*)(brow + kc + b_k0);
      const float4 y1 = *(const float4*)(brow + kc + b_k0 + 4);
      bv8[0]=y0.x; bv8[1]=y0.y; bv8[2]=y0.z; bv8[3]=y0.w;
      bv8[4]=y1.x; bv8[5]=y1.y; bv8[6]=y1.z; bv8[7]=y1.w;
    }
    __syncthreads();              // previous tile fully consumed
    #pragma unroll
    for (int i = 0; i < 8; i++) As[a_k0 + i][a_m] = av8[i];
    #pragma unroll
    for (int i = 0; i < 8; i++) Bs[b_k0 + i][b_n] = bv8[i];
    __syncthreads();
    #pragma unroll
    for (int k = 0; k < 16; k++) {
      const float4 a0 = *(const float4*)&As[k][tm*8];
      const float4 a1 = *(const float4*)&As[k][tm*8+4];
      const float4 b0 = *(const float4*)&Bs[k][tn*8];
      const float4 b1 = *(const float4*)&Bs[k][tn*8+4];
      const float av[8] = {a0.x,a0.y,a0.z,a0.w,a1.x,a1.y,a1.z,a1.w};
      const float bv[8] = {b0.x,b0.y,b0.z,b0.w,b1.x,b1.y,b1.z,b1.w};
      #pragma unroll
      for (int i = 0; i < 8; i++)
        #pragma unroll
        for (int j = 0; j < 8; j++)
          acc[i][j] += av[i] * bv[j];
    }
  }

  if (MODE == 0) {
    float bj[8];
    #pragma unroll
    for (int j = 0; j < 8; j++) bj[j] = bias[nbase + tn*8 + j];
    #pragma unroll
    for (int i = 0; i < 8; i++) {
      float* orow = out + (size_t)(mbase + tm*8 + i) * 768 + nbase + tn*8;
      *(float4*)(orow)     = make_float4(acc[i][0]+bj[0], acc[i][1]+bj[1], acc[i][2]+bj[2], acc[i][3]+bj[3]);
      *(float4*)(orow + 4) = make_float4(acc[i][4]+bj[4], acc[i][5]+bj[5], acc[i][6]+bj[6], acc[i][7]+bj[7]);
    }
  } else if (MODE == 1) {
    float bj[8];
    #pragma unroll
    for (int j = 0; j < 8; j++) bj[j] = bias[nbase + tn*8 + j];
    #pragma unroll
    for (int i = 0; i < 8; i++) {
      float* orow = out + (size_t)(mbase + tm*8 + i) * 128 + nbase + tn*8;
      #pragma unroll
      for (int j = 0; j < 8; j++) orow[j] = tanhf(acc[i][j] + bj[j]);
    }
  } else {
    float ps[8];
    float bj[8], wj[8];
    #pragma unroll
    for (int j = 0; j < 8; j++) { bj[j] = bias[nbase + tn*8 + j]; wj[j] = Wa2[nbase + tn*8 + j]; }
    #pragma unroll
    for (int i = 0; i < 8; i++) {
      float s = 0.f;
      #pragma unroll
      for (int j = 0; j < 8; j++) s += tanhf(acc[i][j] + bj[j]) * wj[j];
      ps[i] = s;
    }
    __syncthreads();                       // As free for reuse
    float* red = &As[0][0];                // 2112 floats >= 2048
    #pragma unroll
    for (int i = 0; i < 8; i++) red[(tm*8 + i)*16 + tn] = ps[i];
    __syncthreads();
    if (tid < 128) {
      float s = 0.f;
      #pragma unroll
      for (int q = 0; q < 16; q++) s += red[tid*16 + q];
      atomicAdd(out + mbase + tid, s);     // ba2 omitted: softmax shift-invariant
    }
  }
}

// =====================================================================
// Persistent flag-synced GRU scan over one chunk of CH steps.
// 256 blocks = 16 batch-groups (32 b each) x 16 col-groups (16 h-cols).
// W_hh slice resident in LDS for whole kernel. h double-buffered in ws,
// accessed with agent-scope (sc0/sc1) atomics for cross-XCD coherence.
// =====================================================================
__global__ __launch_bounds__(256)
void k_scan(const float* __restrict__ gi, const float* __restrict__ Whh,
            const float* __restrict__ bhh, float* hbuf,
            float* __restrict__ outputs, int* flags, int c)
{
  const int tid  = threadIdx.x;
  const int bb   = blockIdx.x >> 4;     // batch group
  const int jb   = blockIdx.x & 15;     // col group
  const int wave = tid >> 6, lane = tid & 63;
  const int jl   = lane & 15, bgl = lane >> 4;
  const int col  = jb*16 + jl;
  const int bloc = wave*8 + bgl*2;      // block-local batch (owns bloc, bloc+1)
  const int b0   = bb*32 + bloc;

  __shared__ float Wl[48*260];          // rows: gate*16 + jl, padded to 260
  __shared__ float Hl[32*260];          // staged h rows, padded

  for (int idx = tid; idx < 48*256; idx += 256) {
    int r = idx >> 8, k = idx & 255;
    Wl[r*260 + k] = Whh[(size_t)(((r >> 4) << 8) + jb*16 + (r & 15)) * 256 + k];
  }
  const float bh0 = bhh[col], bh1 = bhh[256 + col], bh2 = bhh[512 + col];
  __syncthreads();

  const int srow = tid & 31, sko = (tid >> 5) << 5;

  for (int s = 0; s < CH; s++) {
    const int g = c*CH + s;
    // wait for all col-groups of our batch-group to finish step g-1
    if (tid < 16) {
      while (__hip_atomic_load(&flags[bb*16 + tid], __ATOMIC_RELAXED,
                               __HIP_MEMORY_SCOPE_AGENT) < g)
        __builtin_amdgcn_s_sleep(2);
    }
    __syncthreads();
    // stage h (coherent loads bypass stale L1/L2)
    {
      const float* hr = hbuf + (size_t)(g & 1)*(BATCH*HID)
                      + ((size_t)bb*32 + srow)*HID + sko;
      float v[32];
      #pragma unroll
      for (int i = 0; i < 32; i++)
        v[i] = __hip_atomic_load(hr + i, __ATOMIC_RELAXED, __HIP_MEMORY_SCOPE_AGENT);
      float* hl = &Hl[srow*260 + sko];
      #pragma unroll
      for (int i = 0; i < 8; i++)
        ((float4*)hl)[i] = make_float4(v[4*i], v[4*i+1], v[4*i+2], v[4*i+3]);
    }
    __syncthreads();
    // gh for (2 batches) x (3 gates) at column `col`
    float acc[6] = {0,0,0,0,0,0};
    {
      const float* w0 = &Wl[jl*260];
      const float* w1 = &Wl[(16 + jl)*260];
      const float* w2 = &Wl[(32 + jl)*260];
      const float* h0 = &Hl[bloc*260];
      const float* h1 = &Hl[(bloc + 1)*260];
      #pragma unroll 4
      for (int k4 = 0; k4 < 64; k4++) {
        const float4 wr = ((const float4*)w0)[k4];
        const float4 wz = ((const float4*)w1)[k4];
        const float4 wn = ((const float4*)w2)[k4];
        const float4 ha = ((const float4*)h0)[k4];
        const float4 hb = ((const float4*)h1)[k4];
        acc[0] += wr.x*ha.x + wr.y*ha.y + wr.z*ha.z + wr.w*ha.w;
        acc[1] += wz.x*ha.x + wz.y*ha.y + wz.z*ha.z + wz.w*ha.w;
        acc[2] += wn.x*ha.x + wn.y*ha.y + wn.z*ha.z + wn.w*ha.w;
        acc[3] += wr.x*hb.x + wr.y*hb.y + wr.z*hb.z + wr.w*hb.w;
        acc[4] += wz.x*hb.x + wz.y*hb.y + wz.z*hb.z + wz.w*hb.w;
        acc[5] += wn.x*hb.x + wn.y*hb.y + wn.z*hb.z + wn.w*hb.w;
      }
    }
    // GRU gate update
    const float* gib = gi + ((size_t)s << 9) * 768;
    float* hw = hbuf + (size_t)((g + 1) & 1)*(BATCH*HID);
    float* orow = outputs + (size_t)g*(BATCH*HID);
    #pragma unroll
    for (int ib = 0; ib < 2; ib++) {
      const int b = b0 + ib;
      const float* gr = gib + (size_t)b*768 + col;
      const float i_r = gr[0], i_z = gr[256], i_n = gr[512];   // b_ih already folded in
      const float g_r = acc[ib*3+0] + bh0;
      const float g_z = acc[ib*3+1] + bh1;
      const float g_n = acc[ib*3+2] + bh2;
      const float r = 1.f/(1.f + expf(-(i_r + g_r)));
      const float z = 1.f/(1.f + expf(-(i_z + g_z)));
      const float nn = tanhf(i_n + r*g_n);
      const float hp = Hl[(bloc + ib)*260 + col];
      const float hn = (1.f - z)*nn + z*hp;
      __hip_atomic_store(&hw[(size_t)b*HID + col], hn,
                         __ATOMIC_RELAXED, __HIP_MEMORY_SCOPE_AGENT);
      orow[(size_t)b*HID + col] = hn;
    }
    __syncthreads();   // all waves drained (vmcnt 0) + Hl reads done
    if (tid == 0)
      __hip_atomic_store(&flags[bb*16 + jb], g + 1,
                         __ATOMIC_RELEASE, __HIP_MEMORY_SCOPE_AGENT);
  }
}

// =====================================================================
// Action probabilities: softmax3((h_{t-1} @ W_act^T + b_act)) per stack
// =====================================================================
__global__ __launch_bounds__(256)
void k_act(const float* __restrict__ outputs, const float* __restrict__ Wact,
           const float* __restrict__ bact, float* __restrict__ probs)
{
  __shared__ float Wl[6][260];
  for (int idx = threadIdx.x; idx < 6*256; idx += 256)
    Wl[idx >> 8][idx & 255] = Wact[idx];
  __syncthreads();
  const int m = blockIdx.x*256 + threadIdx.x;
  const int t = m >> 9;
  const float* row = (t == 0) ? nullptr : (outputs + (size_t)(m - 512)*HID);
  float acc[6] = {0,0,0,0,0,0};
  if (row) {
    for (int k4 = 0; k4 < 64; k4++) {
      const float4 x = ((const float4*)row)[k4];
      #pragma unroll
      for (int j = 0; j < 6; j++) {
        const float4 w = *(const float4*)&Wl[j][k4*4];
        acc[j] += x.x*w.x + x.y*w.y + x.z*w.z + x.w*w.w;
      }
    }
  }
  #pragma unroll
  for (int j = 0; j < 6; j++) acc[j] += bact[j];
  #pragma unroll
  for (int n = 0; n < 2; n++) {
    const float l0 = acc[n*3], l1 = acc[n*3+1], l2 = acc[n*3+2];
    const float mx = fmaxf(l0, fmaxf(l1, l2));
    const float e0 = expf(l0-mx), e1 = expf(l1-mx), e2 = expf(l2-mx);
    const float inv = 1.f/(e0+e1+e2);
    probs[(size_t)m*6 + n*3 + 0] = e0*inv;
    probs[(size_t)m*6 + n*3 + 1] = e1*inv;
    probs[(size_t)m*6 + n*3 + 2] = e2*inv;
  }
}

// =====================================================================
// Stack recurrence: lane = ELEM column, 64-deep stack in registers.
// =====================================================================
__global__ __launch_bounds__(256)
void k_stack(const float* __restrict__ probs, const float* __restrict__ push,
             const float* __restrict__ empty, float* __restrict__ stko)
{
  const int wave = threadIdx.x >> 6, lane = threadIdx.x & 63;
  const int p = blockIdx.x*4 + wave, b = p >> 1, n = p & 1;
  const float e = empty[lane];
  float s[64];
  #pragma unroll
  for (int i = 0; i < 64; i++) s[i] = e;
  const float* pr = probs + (size_t)b*6 + n*3;
  const float* pv = push + (size_t)b*128 + n*64 + lane;
  float pp = pr[0], po = pr[1], pn = pr[2], pvv = pv[0];
  for (int t = 0; t < 256; t++) {
    const float cpp = pp, cpo = po, cpn = pn, cpv = pvv;
    if (t < 255) {   // prefetch next step
      const float* prn = pr + (size_t)(t + 1)*3072;
      pp = prn[0]; po = prn[1]; pn = prn[2];
      pvv = pv[(size_t)(t + 1)*65536];
    }
    float pm1 = s[0];
    s[0] = cpp*cpv;                       // row0 overwritten by push
    #pragma unroll
    for (int i = 1; i < 63; i++) {
      const float cur = s[i];
      s[i] = cpp*pm1 + cpo*s[i+1] + cpn*cur;
      pm1 = cur;
    }
    // s[63] stays = empty (reference overwrites row 63 each step)
  }
  float* o = stko + ((size_t)b*2 + n)*64*64 + lane;
  #pragma unroll
  for (int i = 0; i < 64; i++) o[(size_t)i*64] = s[i];
}

// =====================================================================
// Attention: masked softmax over t, then weighted sum of outputs.
// =====================================================================
__global__ __launch_bounds__(256)
void k_attn_final(const float* __restrict__ araw, const int* __restrict__ tokens,
                  const float* __restrict__ outputs, float* __restrict__ finalh)
{
  const int b = blockIdx.x, tid = threadIdx.x;
  __shared__ float red[256];
  __shared__ float wts[256];
  const float raw = araw[(size_t)tid*BATCH + b];
  const int   tk  = tokens[(size_t)tid*BATCH + b];
  const float x = (tk == 0) ? -INFINITY : raw;
  red[tid] = x; __syncthreads();
  for (int st = 128; st > 0; st >>= 1) {
    if (tid < st) red[tid] = fmaxf(red[tid], red[tid + st]);
    __syncthreads();
  }
  const float M = red[0]; __syncthreads();
  const float ev = expf(x - M);           // masked -> 0
  red[tid] = ev; __syncthreads();
  for (int st = 128; st > 0; st >>= 1) {
    if (tid < st) red[tid] += red[tid + st];
    __syncthreads();
  }
  const float Ssum = red[0]; __syncthreads();
  wts[tid] = ev / Ssum; __syncthreads();
  float acc = 0.f;
  for (int t = 0; t < 256; t++)
    acc += wts[t] * outputs[(size_t)t*(BATCH*HID) + (size_t)b*HID + tid];
  finalh[(size_t)b*HID + tid] = acc;
}

// =====================================================================
extern "C" void kernel_launch(void* const* d_in, const int* in_sizes, int n_in,
                              void* d_out, int out_size, void* d_ws, size_t ws_size,
                              hipStream_t stream)
{
  const int*   tokens = (const int*)  d_in[0];
  const float* emb    = (const float*)d_in[1];
  const float* W_ih   = (const float*)d_in[2];
  const float* W_hh   = (const float*)d_in[3];
  const float* b_ih   = (const float*)d_in[4];
  const float* b_hh   = (const float*)d_in[5];
  const float* W_act  = (const float*)d_in[6];
  const float* b_act  = (const float*)d_in[7];
  const float* W_stk  = (const float*)d_in[8];
  const float* b_stk  = (const float*)d_in[9];
  const float* empty  = (const float*)d_in[10];
  // d_in[11], d_in[12] are W_up/W_down shift matrices: semantics hardcoded
  const float* Wa1    = (const float*)d_in[13];
  const float* ba1    = (const float*)d_in[14];
  const float* Wa2    = (const float*)d_in[15];

  float* outputs = (float*)d_out;
  float* finalh  = outputs + (size_t)S_LEN*BATCH*HID;
  float* stk_out = finalh + (size_t)BATCH*HID;

  if (ws_size < WS_FLOATS * sizeof(float)) return;   // signal: ws too small
  float* ws    = (float*)d_ws;
  float* gi    = ws + OFF_GI;
  float* hbuf  = ws + OFF_H;
  float* probs = ws + OFF_PROBS;
  float* pushv = ws + OFF_PUSH;
  float* araw  = ws + OFF_ARAW;
  int*   flags = (int*)(ws + OFF_FLAGS);

  hipMemsetAsync(hbuf, 0, N_H*sizeof(float), stream);
  hipMemsetAsync(flags, 0, N_FLAGS*sizeof(int), stream);
  hipMemsetAsync(araw, 0, N_ARAW*sizeof(float), stream);

  for (int c = 0; c < NCH; c++) {
    k_gemm<0><<<dim3(CH*BATCH/128, 6), 256, 0, stream>>>(
        nullptr, tokens + (size_t)c*CH*BATCH, emb, W_ih, b_ih, nullptr, gi);
    k_scan<<<256, 256, 0, stream>>>(gi, W_hh, b_hh, hbuf, outputs, flags, c);
  }
  k_gemm<1><<<dim3(1024, 1), 256, 0, stream>>>(
      outputs, nullptr, nullptr, W_stk, b_stk, nullptr, pushv);
  k_act<<<512, 256, 0, stream>>>(outputs, W_act, b_act, probs);
  k_stack<<<256, 256, 0, stream>>>(probs, pushv, empty, stk_out);
  k_gemm<2><<<dim3(1024, 2), 256, 0, stream>>>(
      outputs, nullptr, nullptr, Wa1, ba1, Wa2, araw);
  k_attn_final<<<512, 256, 0, stream>>>(araw, tokens, outputs, finalh);
}

// Round 3
// 4881.837 us; speedup vs baseline: 1.4927x; 1.4927x over previous
//
#include <hip/hip_runtime.h>
#include <stdint.h>

// Problem dims
#define S_LEN 256
#define BATCH 512
#define HID   256
#define CH    64            // timestep chunk for gi precompute
#define NCH   (S_LEN/CH)

// ---------------- workspace layout (floats) ----------------
#define OFF_GI    0ull
#define N_GI      ((size_t)CH*BATCH*768)        // 25,165,824
#define OFF_PROBS (OFF_GI + N_GI)
#define N_PROBS   ((size_t)S_LEN*BATCH*6)
#define OFF_PUSH  (OFF_PROBS + N_PROBS)
#define N_PUSH    ((size_t)S_LEN*BATCH*128)
#define OFF_ARAW  (OFF_PUSH + N_PUSH)
#define N_ARAW    ((size_t)S_LEN*BATCH)
#define OFF_FLAGS (OFF_ARAW + N_ARAW)
#define N_FLAGS   256ull
#define WS_FLOATS (OFF_FLAGS + N_FLAGS)

// =====================================================================
// Generic 128x128x256 fp32 GEMM, A is [M,256] (maybe gathered/shifted),
// W is [N][256] row-major (we compute A @ W^T).
// MODE 0: A = masked embedding gather (gi precompute), out = A@W^T + bias
// MODE 1: A = outputs shifted by one timestep, out = tanh(A@W^T + bias)
// MODE 2: A = outputs, epilogue: araw[m] += sum_n tanh(C+ba1[n])*Wa2[n]
// =====================================================================
template<int MODE>
__global__ __launch_bounds__(256)
void k_gemm(const float* __restrict__ Asrc,
            const int*   __restrict__ tok,
            const float* __restrict__ emb,
            const float* __restrict__ W,
            const float* __restrict__ bias,
            const float* __restrict__ Wa2,
            float* __restrict__ out)
{
  const int tid   = threadIdx.x;
  const int mbase = blockIdx.x * 128;
  const int nbase = blockIdx.y * 128;
  __shared__ float As[16][132];
  __shared__ float Bs[16][132];
  const int tm = tid & 15, tn = tid >> 4;

  float acc[8][8];
  #pragma unroll
  for (int i = 0; i < 8; i++)
    #pragma unroll
    for (int j = 0; j < 8; j++) acc[i][j] = 0.f;

  const int a_m = tid & 127, a_k0 = (tid >> 7) << 3;   // 2 threads per row, 8 k each
  const int b_n = tid & 127, b_k0 = a_k0;

  const float* arow;
  if (MODE == 0) {
    int t = tok[mbase + a_m];
    arow = (t == 0) ? nullptr : (emb + (size_t)t * HID);        // PAD mask
  } else if (MODE == 1) {
    int m = mbase + a_m;
    arow = (m < BATCH) ? nullptr : (Asrc + (size_t)(m - BATCH) * HID); // h_{t-1}; t=0 -> 0
  } else {
    arow = Asrc + (size_t)(mbase + a_m) * HID;
  }
  const float* brow = W + (size_t)(nbase + b_n) * HID;

  for (int kc = 0; kc < 256; kc += 16) {
    float av8[8], bv8[8];
    if (arow) {
      const float4 x0 = *(const float4*)(arow + kc + a_k0);
      const float4 x1 = *(const float4*)(arow + kc + a_k0 + 4);
      av8[0]=x0.x; av8[1]=x0.y; av8[2]=x0.z; av8[3]=x0.w;
      av8[4]=x1.x; av8[5]=x1.y; av8[6]=x1.z; av8[7]=x1.w;
    } else {
      #pragma unroll
      for (int i = 0; i < 8; i++) av8[i] = 0.f;
    }
    {
      const float4 y0 = *(const float4*)(brow + kc + b_k0);
      const float4 y1 = *(const float4*)(brow + kc + b_k0 + 4);
      bv8[0]=y0.x; bv8[1]=y0.y; bv8[2]=y0.z; bv8[3]=y0.w;
      bv8[4]=y1.x; bv8[5]=y1.y; bv8[6]=y1.z; bv8[7]=y1.w;
    }
    __syncthreads();              // previous tile fully consumed
    #pragma unroll
    for (int i = 0; i < 8; i++) As[a_k0 + i][a_m] = av8[i];
    #pragma unroll
    for (int i = 0; i < 8; i++) Bs[b_k0 + i][b_n] = bv8[i];
    __syncthreads();
    #pragma unroll
    for (int k = 0; k < 16; k++) {
      const float4 a0 = *(const float4*)&As[k][tm*8];
      const float4 a1 = *(const float4*)&As[k][tm*8+4];
      const float4 b0 = *(const float4*)&Bs[k][tn*8];
      const float4 b1 = *(const float4*)&Bs[k][tn*8+4];
      const float av[8] = {a0.x,a0.y,a0.z,a0.w,a1.x,a1.y,a1.z,a1.w};
      const float bv[8] = {b0.x,b0.y,b0.z,b0.w,b1.x,b1.y,b1.z,b1.w};
      #pragma unroll
      for (int i = 0; i < 8; i++)
        #pragma unroll
        for (int j = 0; j < 8; j++)
          acc[i][j] += av[i] * bv[j];
    }
  }

  if (MODE == 0) {
    float bj[8];
    #pragma unroll
    for (int j = 0; j < 8; j++) bj[j] = bias[nbase + tn*8 + j];
    #pragma unroll
    for (int i = 0; i < 8; i++) {
      float* orow = out + (size_t)(mbase + tm*8 + i) * 768 + nbase + tn*8;
      *(float4*)(orow)     = make_float4(acc[i][0]+bj[0], acc[i][1]+bj[1], acc[i][2]+bj[2], acc[i][3]+bj[3]);
      *(float4*)(orow + 4) = make_float4(acc[i][4]+bj[4], acc[i][5]+bj[5], acc[i][6]+bj[6], acc[i][7]+bj[7]);
    }
  } else if (MODE == 1) {
    float bj[8];
    #pragma unroll
    for (int j = 0; j < 8; j++) bj[j] = bias[nbase + tn*8 + j];
    #pragma unroll
    for (int i = 0; i < 8; i++) {
      float* orow = out + (size_t)(mbase + tm*8 + i) * 128 + nbase + tn*8;
      #pragma unroll
      for (int j = 0; j < 8; j++) orow[j] = tanhf(acc[i][j] + bj[j]);
    }
  } else {
    float ps[8];
    float bj[8], wj[8];
    #pragma unroll
    for (int j = 0; j < 8; j++) { bj[j] = bias[nbase + tn*8 + j]; wj[j] = Wa2[nbase + tn*8 + j]; }
    #pragma unroll
    for (int i = 0; i < 8; i++) {
      float s = 0.f;
      #pragma unroll
      for (int j = 0; j < 8; j++) s += tanhf(acc[i][j] + bj[j]) * wj[j];
      ps[i] = s;
    }
    __syncthreads();                       // As free for reuse
    float* red = &As[0][0];                // 2112 floats >= 2048
    #pragma unroll
    for (int i = 0; i < 8; i++) red[(tm*8 + i)*16 + tn] = ps[i];
    __syncthreads();
    if (tid < 128) {
      float s = 0.f;
      #pragma unroll
      for (int q = 0; q < 16; q++) s += red[tid*16 + q];
      atomicAdd(out + mbase + tid, s);     // ba2 omitted: softmax shift-invariant
    }
  }
}

// =====================================================================
// Batch-parallel flag-synced GRU scan.
// 256 blocks = 32 groups (16 batches each) x 8 col-blocks (32 h-cols).
// Exchange h THROUGH the outputs array: producers store with agent-scope
// (IF-visible) atomics; consumers read with plain coalesced float4 loads
// (every address is cold -> no stale-cache hazard; kernel-boundary acquire
// handles cross-replay staleness).
// W_hh slice (96 rows) LDS-resident in conflict-free k-major layout.
// =====================================================================
__global__ __launch_bounds__(256)
void k_scan(const float* __restrict__ gi, const float* __restrict__ Whh,
            const float* __restrict__ bhh,
            float* outputs, int* flags, int c)
{
  const int tid = threadIdx.x;
  const int grp = blockIdx.x >> 3;       // 0..31 : batch group (16 batches)
  const int cb  = blockIdx.x & 7;        // 0..7  : col block (32 h-cols)
  const int jl  = tid & 31;              // col within block
  const int bp  = tid >> 5;              // batch-pair 0..7
  const int col = cb*32 + jl;
  const int bloc0  = bp*2;               // local batches bloc0, bloc0+1
  const int bglob0 = grp*16 + bloc0;

  // k-major W tile: Wl4[k4*96 + gate*32 + jl] -> lanes read 512B contiguous
  __shared__ float4 Wl4[6144];           // 96 KB
  __shared__ float  Hl[16*260];          // 16.6 KB, row stride 260 (1040B, 16B-aligned)

  {
    const float4* W4 = (const float4*)Whh;
    for (int f = tid; f < 6144; f += 256) {
      const int k4 = f & 63, row = f >> 6;          // row = gate*32 + jl2
      const int g = row >> 5, jl2 = row & 31;
      Wl4[k4*96 + row] = W4[(size_t)((g<<8) + cb*32 + jl2)*64 + k4];
    }
  }
  const float bh0 = bhh[col], bh1 = bhh[256 + col], bh2 = bhh[512 + col];

  for (int s = 0; s < CH; s++) {
    const int t = c*CH + s;
    // ---- gi prefetch (independent of the exchange) ----
    const float* g0 = gi + ((size_t)s*BATCH + bglob0)*768 + col;
    const float i_r0 = g0[0],   i_z0 = g0[256],  i_n0 = g0[512];
    const float i_r1 = g0[768], i_z1 = g0[1024], i_n1 = g0[1280];
    // ---- wait for the group's 8 producers to finish step t-1 ----
    if (tid < 8) {
      while (__hip_atomic_load(&flags[grp*8 + tid], __ATOMIC_RELAXED,
                               __HIP_MEMORY_SCOPE_AGENT) < t) {}
    }
    __syncthreads();
    // ---- stage h_{t-1} (16 batches x 256 cols), coalesced ----
    if (t == 0) {
      const float4 z = make_float4(0.f, 0.f, 0.f, 0.f);
      #pragma unroll
      for (int i = 0; i < 4; i++) {
        const int f = i*256 + tid;                  // float4 index in 16x256
        *(float4*)&Hl[(f >> 6)*260 + (f & 63)*4] = z;
      }
    } else {
      const float4* hsrc = (const float4*)(outputs + ((size_t)(t-1)*BATCH + grp*16)*HID);
      float4 hv[4];
      #pragma unroll
      for (int i = 0; i < 4; i++) hv[i] = hsrc[i*256 + tid];
      #pragma unroll
      for (int i = 0; i < 4; i++) {
        const int f = i*256 + tid;
        *(float4*)&Hl[(f >> 6)*260 + (f & 63)*4] = hv[i];
      }
    }
    __syncthreads();
    // ---- gh dot: 2 batches x 3 gates at column `col` ----
    float a0=0.f,a1=0.f,a2=0.f,a3=0.f,a4=0.f,a5=0.f;
    const float4* h0p = (const float4*)&Hl[bloc0*260];
    const float4* h1p = (const float4*)&Hl[(bloc0+1)*260];
    #pragma unroll 4
    for (int k4 = 0; k4 < 64; k4++) {
      const float4 wr = Wl4[k4*96 + jl];
      const float4 wz = Wl4[k4*96 + 32 + jl];
      const float4 wn = Wl4[k4*96 + 64 + jl];
      const float4 ha = h0p[k4];
      const float4 hb = h1p[k4];
      a0 += wr.x*ha.x + wr.y*ha.y + wr.z*ha.z + wr.w*ha.w;
      a1 += wz.x*ha.x + wz.y*ha.y + wz.z*ha.z + wz.w*ha.w;
      a2 += wn.x*ha.x + wn.y*ha.y + wn.z*ha.z + wn.w*ha.w;
      a3 += wr.x*hb.x + wr.y*hb.y + wr.z*hb.z + wr.w*hb.w;
      a4 += wz.x*hb.x + wz.y*hb.y + wz.z*hb.z + wz.w*hb.w;
      a5 += wn.x*hb.x + wn.y*hb.y + wn.z*hb.z + wn.w*hb.w;
    }
    // ---- GRU gate update ----
    const float hp0 = Hl[bloc0*260 + col];
    const float hp1 = Hl[(bloc0+1)*260 + col];
    const float r0 = 1.f/(1.f + expf(-(i_r0 + a0 + bh0)));
    const float z0 = 1.f/(1.f + expf(-(i_z0 + a1 + bh1)));
    const float n0 = tanhf(i_n0 + r0*(a2 + bh2));
    const float hn0 = (1.f - z0)*n0 + z0*hp0;
    const float r1 = 1.f/(1.f + expf(-(i_r1 + a3 + bh0)));
    const float z1 = 1.f/(1.f + expf(-(i_z1 + a4 + bh1)));
    const float n1 = tanhf(i_n1 + r1*(a5 + bh2));
    const float hn1 = (1.f - z1)*n1 + z1*hp1;
    float* orow = outputs + ((size_t)t*BATCH + bglob0)*HID + col;
    __hip_atomic_store(orow,       hn0, __ATOMIC_RELAXED, __HIP_MEMORY_SCOPE_AGENT);
    __hip_atomic_store(orow + HID, hn1, __ATOMIC_RELAXED, __HIP_MEMORY_SCOPE_AGENT);
    __syncthreads();   // all waves' stores drained (vmcnt 0) + Hl reads done
    if (tid == 0)
      __hip_atomic_store(&flags[grp*8 + cb], t + 1,
                         __ATOMIC_RELEASE, __HIP_MEMORY_SCOPE_AGENT);
  }
}

// =====================================================================
// Action probabilities: softmax3((h_{t-1} @ W_act^T + b_act)) per stack
// =====================================================================
__global__ __launch_bounds__(256)
void k_act(const float* __restrict__ outputs, const float* __restrict__ Wact,
           const float* __restrict__ bact, float* __restrict__ probs)
{
  __shared__ float Wl[6][260];
  for (int idx = threadIdx.x; idx < 6*256; idx += 256)
    Wl[idx >> 8][idx & 255] = Wact[idx];
  __syncthreads();
  const int m = blockIdx.x*256 + threadIdx.x;
  const int t = m >> 9;
  const float* row = (t == 0) ? nullptr : (outputs + (size_t)(m - 512)*HID);
  float acc[6] = {0,0,0,0,0,0};
  if (row) {
    for (int k4 = 0; k4 < 64; k4++) {
      const float4 x = ((const float4*)row)[k4];
      #pragma unroll
      for (int j = 0; j < 6; j++) {
        const float4 w = *(const float4*)&Wl[j][k4*4];
        acc[j] += x.x*w.x + x.y*w.y + x.z*w.z + x.w*w.w;
      }
    }
  }
  #pragma unroll
  for (int j = 0; j < 6; j++) acc[j] += bact[j];
  #pragma unroll
  for (int n = 0; n < 2; n++) {
    const float l0 = acc[n*3], l1 = acc[n*3+1], l2 = acc[n*3+2];
    const float mx = fmaxf(l0, fmaxf(l1, l2));
    const float e0 = expf(l0-mx), e1 = expf(l1-mx), e2 = expf(l2-mx);
    const float inv = 1.f/(e0+e1+e2);
    probs[(size_t)m*6 + n*3 + 0] = e0*inv;
    probs[(size_t)m*6 + n*3 + 1] = e1*inv;
    probs[(size_t)m*6 + n*3 + 2] = e2*inv;
  }
}

// =====================================================================
// Stack recurrence: lane = ELEM column, 64-deep stack in registers.
// =====================================================================
__global__ __launch_bounds__(256)
void k_stack(const float* __restrict__ probs, const float* __restrict__ push,
             const float* __restrict__ empty, float* __restrict__ stko)
{
  const int wave = threadIdx.x >> 6, lane = threadIdx.x & 63;
  const int p = blockIdx.x*4 + wave, b = p >> 1, n = p & 1;
  const float e = empty[lane];
  float s[64];
  #pragma unroll
  for (int i = 0; i < 64; i++) s[i] = e;
  const float* pr = probs + (size_t)b*6 + n*3;
  const float* pv = push + (size_t)b*128 + n*64 + lane;
  float pp = pr[0], po = pr[1], pn = pr[2], pvv = pv[0];
  for (int t = 0; t < 256; t++) {
    const float cpp = pp, cpo = po, cpn = pn, cpv = pvv;
    if (t < 255) {   // prefetch next step
      const float* prn = pr + (size_t)(t + 1)*3072;
      pp = prn[0]; po = prn[1]; pn = prn[2];
      pvv = pv[(size_t)(t + 1)*65536];
    }
    float pm1 = s[0];
    s[0] = cpp*cpv;                       // row0 overwritten by push
    #pragma unroll
    for (int i = 1; i < 63; i++) {
      const float cur = s[i];
      s[i] = cpp*pm1 + cpo*s[i+1] + cpn*cur;
      pm1 = cur;
    }
    // s[63] stays = empty (reference overwrites row 63 each step)
  }
  float* o = stko + ((size_t)b*2 + n)*64*64 + lane;
  #pragma unroll
  for (int i = 0; i < 64; i++) o[(size_t)i*64] = s[i];
}

// =====================================================================
// Attention: masked softmax over t, then weighted sum of outputs.
// =====================================================================
__global__ __launch_bounds__(256)
void k_attn_final(const float* __restrict__ araw, const int* __restrict__ tokens,
                  const float* __restrict__ outputs, float* __restrict__ finalh)
{
  const int b = blockIdx.x, tid = threadIdx.x;
  __shared__ float red[256];
  __shared__ float wts[256];
  const float raw = araw[(size_t)tid*BATCH + b];
  const int   tk  = tokens[(size_t)tid*BATCH + b];
  const float x = (tk == 0) ? -INFINITY : raw;
  red[tid] = x; __syncthreads();
  for (int st = 128; st > 0; st >>= 1) {
    if (tid < st) red[tid] = fmaxf(red[tid], red[tid + st]);
    __syncthreads();
  }
  const float M = red[0]; __syncthreads();
  const float ev = expf(x - M);           // masked -> 0
  red[tid] = ev; __syncthreads();
  for (int st = 128; st > 0; st >>= 1) {
    if (tid < st) red[tid] += red[tid + st];
    __syncthreads();
  }
  const float Ssum = red[0]; __syncthreads();
  wts[tid] = ev / Ssum; __syncthreads();
  float acc = 0.f;
  for (int t = 0; t < 256; t++)
    acc += wts[t] * outputs[(size_t)t*(BATCH*HID) + (size_t)b*HID + tid];
  finalh[(size_t)b*HID + tid] = acc;
}

// =====================================================================
extern "C" void kernel_launch(void* const* d_in, const int* in_sizes, int n_in,
                              void* d_out, int out_size, void* d_ws, size_t ws_size,
                              hipStream_t stream)
{
  const int*   tokens = (const int*)  d_in[0];
  const float* emb    = (const float*)d_in[1];
  const float* W_ih   = (const float*)d_in[2];
  const float* W_hh   = (const float*)d_in[3];
  const float* b_ih   = (const float*)d_in[4];
  const float* b_hh   = (const float*)d_in[5];
  const float* W_act  = (const float*)d_in[6];
  const float* b_act  = (const float*)d_in[7];
  const float* W_stk  = (const float*)d_in[8];
  const float* b_stk  = (const float*)d_in[9];
  const float* empty  = (const float*)d_in[10];
  // d_in[11], d_in[12] are W_up/W_down shift matrices: semantics hardcoded
  const float* Wa1    = (const float*)d_in[13];
  const float* ba1    = (const float*)d_in[14];
  const float* Wa2    = (const float*)d_in[15];

  float* outputs = (float*)d_out;
  float* finalh  = outputs + (size_t)S_LEN*BATCH*HID;
  float* stk_out = finalh + (size_t)BATCH*HID;

  if (ws_size < WS_FLOATS * sizeof(float)) return;   // signal: ws too small
  float* ws    = (float*)d_ws;
  float* gi    = ws + OFF_GI;
  float* probs = ws + OFF_PROBS;
  float* pushv = ws + OFF_PUSH;
  float* araw  = ws + OFF_ARAW;
  int*   flags = (int*)(ws + OFF_FLAGS);

  hipMemsetAsync(flags, 0, N_FLAGS*sizeof(int), stream);
  hipMemsetAsync(araw, 0, N_ARAW*sizeof(float), stream);

  for (int c = 0; c < NCH; c++) {
    k_gemm<0><<<dim3(CH*BATCH/128, 6), 256, 0, stream>>>(
        nullptr, tokens + (size_t)c*CH*BATCH, emb, W_ih, b_ih, nullptr, gi);
    k_scan<<<256, 256, 0, stream>>>(gi, W_hh, b_hh, outputs, flags, c);
  }
  k_gemm<1><<<dim3(1024, 1), 256, 0, stream>>>(
      outputs, nullptr, nullptr, W_stk, b_stk, nullptr, pushv);
  k_act<<<512, 256, 0, stream>>>(outputs, W_act, b_act, probs);
  k_stack<<<256, 256, 0, stream>>>(probs, pushv, empty, stk_out);
  k_gemm<2><<<dim3(1024, 2), 256, 0, stream>>>(
      outputs, nullptr, nullptr, Wa1, ba1, Wa2, araw);
  k_attn_final<<<512, 256, 0, stream>>>(araw, tokens, outputs, finalh);
}